// Round 13
// baseline (118.559 us; speedup 1.0000x reference)
//
#include <hip/hip_runtime.h>
#include <math.h>

#define RES 2048
#define NB  256

// DIAGNOSTIC ROUND: REP=8 outer repetitions of the identical computation.
// dur_us(R13) = 8*K + OH vs dur_us(R12) = K + OH pins kernel time K and
// harness overhead OH; the 8x duration forces ewald_fused into rocprof's
// top-5 so we finally see its MfmaUtil/VALUBusy/VGPR/conflict counters.
// Output is written identically every rep -> deterministic, validates.
#define REP 8

typedef _Float16 f16;
typedef __fp16   fp16x2 __attribute__((ext_vector_type(2)));
typedef _Float16 f16x8 __attribute__((ext_vector_type(8)));
typedef float    f32x16 __attribute__((ext_vector_type(16)));

#define BM 128
#define BN 128
#define BK 16
#define NKT (NB / BK)      // 16 k-tiles
#define PL  (BM * BK)      // elements per plane (2048)

#define STEP (2.0f / 2047.0f)

__device__ __forceinline__ f16x8 neg8(f16x8 v) {
    union { f16x8 h; unsigned int u[4]; } x;
    x.h = v;
    #pragma unroll
    for (int i = 0; i < 4; ++i) x.u[i] ^= 0x80008000u;
    return x.h;
}

__device__ __forceinline__ unsigned int pk2(float lo, float hi) {
    union { fp16x2 h; unsigned int u; } x;
    x.h = __builtin_amdgcn_cvt_pkrtz(lo, hi);
    return x.u;
}

__device__ __forceinline__ int swzE(int row, int k) {
    return (row * BK + k) ^ ((row & 7) << 3);
}

__global__ __launch_bounds__(512) void ewald_fused(
    const float* __restrict__ theta, const float* __restrict__ reA,
    const float* __restrict__ imA, const float* __restrict__ x0A,
    const float* __restrict__ y0A, const float* __restrict__ lsA,
    const float* __restrict__ X, const float* __restrict__ Y,
    float* __restrict__ out)
{
    __shared__ f16 smA[2][2][PL];
    __shared__ f16 smB[2][2][PL];
    __shared__ float4 sP0[NB];      // {kx, ky, px, py}
    __shared__ float4 sP1[NB];      // {re, im, 1/sigma^2, -}

    const int t    = threadIdx.x;
    const int lane = t & 63;
    const int wave = t >> 6;
    const int wm   = wave >> 2;
    const int wn   = wave & 3;
    const int la   = lane & 31;
    const int lg   = lane >> 5;

    const int flat = blockIdx.x;
    const int swz  = (flat & 7) * 32 + (flat >> 3);
    const int m0   = (swz >> 4) * BM;
    const int n0   = (swz & 15) * BN;

    if (t < NB) {
        const int b = t;
        const float th = theta[b];
        const float s = __sinf(th), c = __cosf(th);
        const float sig = __expf(lsA[b]) + 0.001f;
        sP0[b] = make_float4(50.0f * c, 50.0f * s, x0A[b], y0A[b]);
        sP1[b] = make_float4(reA[b], imA[b], 1.0f / (sig * sig), 0.0f);
    }
    __syncthreads();

    const int kk2  = (t & 7) * 2;
    const int grp  = t >> 3;
    const int row0 = grp * 2;

    const float xv0 = -1.0f + (float)(m0 + row0)     * STEP;
    const float xv1 = -1.0f + (float)(m0 + row0 + 1) * STEP;
    const float yv0 = -1.0f + (float)(n0 + row0)     * STEP;
    const float yv1 = -1.0f + (float)(n0 + row0 + 1) * STEP;

    const int e0 = swzE(row0, kk2);
    const int e1 = swzE(row0 + 1, kk2);

    #define EVAL(bf, kt)                                                      \
    do {                                                                      \
        const int b0_ = (kt) * BK + kk2;                                      \
        float aR_[2][2], aI_[2][2], bR_[2][2], bI_[2][2];                     \
        _Pragma("unroll")                                                     \
        for (int jb = 0; jb < 2; ++jb) {                                      \
            const float4 p0 = sP0[b0_ + jb];                                  \
            const float4 p1 = sP1[b0_ + jb];                                  \
            _Pragma("unroll")                                                 \
            for (int r = 0; r < 2; ++r) {                                     \
                const float xv = r ? xv1 : xv0;                               \
                const float phx = p0.x * xv;                                  \
                const float sx_ = __sinf(phx), cx_ = __cosf(phx);             \
                const float dx = xv - p0.z;                                   \
                const float ex = __expf(-dx * dx * p1.z);                     \
                aR_[jb][r] = ex * (p1.x * cx_ - p1.y * sx_);                  \
                aI_[jb][r] = ex * (p1.x * sx_ + p1.y * cx_);                  \
                const float yv = r ? yv1 : yv0;                               \
                const float phy = p0.y * yv;                                  \
                const float sy_ = __sinf(phy), cy_ = __cosf(phy);             \
                const float dy = yv - p0.w;                                   \
                const float ey = __expf(-dy * dy * p1.z);                     \
                bR_[jb][r] = ey * cy_;                                        \
                bI_[jb][r] = ey * sy_;                                        \
            }                                                                 \
        }                                                                     \
        _Pragma("unroll")                                                     \
        for (int r = 0; r < 2; ++r) {                                         \
            const int e_ = r ? e1 : e0;                                       \
            *(unsigned int*)&smA[bf][0][e_] = pk2(aR_[0][r], aR_[1][r]);      \
            *(unsigned int*)&smA[bf][1][e_] = pk2(aI_[0][r], aI_[1][r]);      \
            *(unsigned int*)&smB[bf][0][e_] = pk2(bR_[0][r], bR_[1][r]);      \
            *(unsigned int*)&smB[bf][1][e_] = pk2(bI_[0][r], bI_[1][r]);      \
        }                                                                     \
    } while (0)

    const int offA0 = swzE(wm * 64 +  0 + la, lg * 8);
    const int offA1 = swzE(wm * 64 + 32 + la, lg * 8);
    const int offB  = swzE(wn * 32 + la, lg * 8);

    const int gn     = n0 + wn * 32 + la;
    const int gmBase = m0 + wm * 64;

    for (int rep = 0; rep < REP; ++rep) {
        f32x16 accRe0 = (f32x16)0.0f, accIm0 = (f32x16)0.0f;
        f32x16 accRe1 = (f32x16)0.0f, accIm1 = (f32x16)0.0f;

        EVAL(0, 0);
        __syncthreads();

        for (int kt = 0; kt < NKT; ++kt) {
            const int cur = kt & 1;
            const f16x8 aR0 = *(const f16x8*)&smA[cur][0][offA0];
            const f16x8 aR1 = *(const f16x8*)&smA[cur][0][offA1];
            const f16x8 aI0 = *(const f16x8*)&smA[cur][1][offA0];
            const f16x8 aI1 = *(const f16x8*)&smA[cur][1][offA1];
            const f16x8 bR  = *(const f16x8*)&smB[cur][0][offB];
            const f16x8 bI  = *(const f16x8*)&smB[cur][1][offB];
            const f16x8 bN  = neg8(bI);

            __builtin_amdgcn_s_setprio(1);
            accRe0 = __builtin_amdgcn_mfma_f32_32x32x16_f16(aR0, bR, accRe0, 0, 0, 0);
            accIm0 = __builtin_amdgcn_mfma_f32_32x32x16_f16(aR0, bI, accIm0, 0, 0, 0);
            accRe1 = __builtin_amdgcn_mfma_f32_32x32x16_f16(aR1, bR, accRe1, 0, 0, 0);
            accIm1 = __builtin_amdgcn_mfma_f32_32x32x16_f16(aR1, bI, accIm1, 0, 0, 0);
            accRe0 = __builtin_amdgcn_mfma_f32_32x32x16_f16(aI0, bN, accRe0, 0, 0, 0);
            accIm0 = __builtin_amdgcn_mfma_f32_32x32x16_f16(aI0, bR, accIm0, 0, 0, 0);
            accRe1 = __builtin_amdgcn_mfma_f32_32x32x16_f16(aI1, bN, accRe1, 0, 0, 0);
            accIm1 = __builtin_amdgcn_mfma_f32_32x32x16_f16(aI1, bR, accIm1, 0, 0, 0);
            __builtin_amdgcn_s_setprio(0);

            if (kt + 1 < NKT)
                EVAL(cur ^ 1, kt + 1);

            __syncthreads();
        }

        #pragma unroll
        for (int r = 0; r < 16; ++r) {
            const int row = (r & 3) + 8 * (r >> 2) + 4 * lg;
            const float er = accRe0[r], ei = accIm0[r];
            out[(size_t)(gmBase + row) * RES + gn] = er * er + ei * ei;
        }
        #pragma unroll
        for (int r = 0; r < 16; ++r) {
            const int row = (r & 3) + 8 * (r >> 2) + 4 * lg;
            const float er = accRe1[r], ei = accIm1[r];
            out[(size_t)(gmBase + 32 + row) * RES + gn] = er * er + ei * ei;
        }
    }
    #undef EVAL
}

// ---------------------------------------------------------------------------
extern "C" void kernel_launch(void* const* d_in, const int* in_sizes, int n_in,
                              void* d_out, int out_size, void* d_ws, size_t ws_size,
                              hipStream_t stream) {
    const float* theta = (const float*)d_in[0];
    const float* reA   = (const float*)d_in[1];
    const float* imA   = (const float*)d_in[2];
    const float* x0A   = (const float*)d_in[3];
    const float* y0A   = (const float*)d_in[4];
    const float* lsA   = (const float*)d_in[5];
    const float* X     = (const float*)d_in[6];
    const float* Y     = (const float*)d_in[7];
    float* out = (float*)d_out;

    ewald_fused<<<256, 512, 0, stream>>>(theta, reA, imA, x0A, y0A, lsA,
                                         X, Y, out);
}

// Round 14
// 22.904 us; speedup vs baseline: 5.1764x; 5.1764x over previous
//
#include <hip/hip_runtime.h>
#include <math.h>

#define RES 2048
#define NB  256

typedef _Float16 f16;
typedef __fp16   fp16x2 __attribute__((ext_vector_type(2)));
typedef _Float16 f16x8 __attribute__((ext_vector_type(8)));
typedef float    f32x16 __attribute__((ext_vector_type(16)));

#define BM 128
#define BN 128
#define BK 32
#define NKT (NB / BK)          // 8 k-tiles
#define PL32 (BM * BK)         // 4096 elements per plane

#define STEP (2.0f / 2047.0f)
#define DD   (16.0f * STEP)    // row stride of the eval recurrence

__device__ __forceinline__ f16x8 neg8(f16x8 v) {
    union { f16x8 h; unsigned int u[4]; } x;
    x.h = v;
    #pragma unroll
    for (int i = 0; i < 4; ++i) x.u[i] ^= 0x80008000u;
    return x.h;
}

__device__ __forceinline__ unsigned int pk2(float lo, float hi) {
    union { fp16x2 h; unsigned int u; } x;
    x.h = __builtin_amdgcn_cvt_pkrtz(lo, hi);
    return x.u;
}

// ---------------------------------------------------------------------------
// Fused kernel, recurrence-eval edition.
// E[i,j] = sum_b A(i,b)*B(j,b) (complex), out = |E|^2.
// Eval: each thread owns 2 beams x 8 rows (rows rg + r*16). Phase+envelope
// advance by EXACT multiplicative recurrence: v *= rho * (cd + i*sd),
// rho *= w, with (cd,sd) = sincos(k*DD) and w = exp(-2*DD^2/sig^2)
// precomputed per beam. 1 init (4 trans) + 7 steps (7 FMA each) per 8 evals
// vs 8x(3 trans + 8 VALU) direct -> ~2x VALU cut (counter-driven: R13
// showed VALUBusy 59% / MfmaUtil 22% -> eval-VALU-bound).
// LDS plane [128][32] f16, swizzle k ^= (row&3)<<3: b128 frag reads
// conflict-free (verified: 8 lanes cover 32 banks), u32 writes 2-way (free).
// 512 threads = 8 waves (2M x 4N); BK=32 -> 8 tiles, 8 barriers.
// ---------------------------------------------------------------------------
__global__ __launch_bounds__(512) void ewald_fused(
    const float* __restrict__ theta, const float* __restrict__ reA,
    const float* __restrict__ imA, const float* __restrict__ x0A,
    const float* __restrict__ y0A, const float* __restrict__ lsA,
    const float* __restrict__ X, const float* __restrict__ Y,
    float* __restrict__ out)
{
    __shared__ f16 smA[2][2][PL32];   // [buf][Re/Im][swizzled row*32+k]
    __shared__ f16 smB[2][2][PL32];
    __shared__ float4 sP0[NB];        // {kx, ky, px, py}
    __shared__ float4 sP1[NB];        // {re, im, is2, DD*is2}
    __shared__ float4 sP2[NB];        // {cos(kx*DD), sin(kx*DD), cos(ky*DD), sin(ky*DD)}
    __shared__ float  sW[NB];         // exp(-2*DD^2*is2)

    const int t    = threadIdx.x;
    const int lane = t & 63;
    const int wave = t >> 6;       // 0..7
    const int wm   = wave >> 2;    // 0..1 -> M offset 64
    const int wn   = wave & 3;     // 0..3 -> N offset 32
    const int la   = lane & 31;
    const int lg   = lane >> 5;

    // XCD-aware swizzle (256 blocks, 8 XCDs)
    const int flat = blockIdx.x;
    const int swz  = (flat & 7) * 32 + (flat >> 3);
    const int m0   = (swz >> 4) * BM;
    const int n0   = (swz & 15) * BN;

    // ---- prologue: per-beam params + recurrence constants ----
    if (t < NB) {
        const int b = t;
        const float th = theta[b];
        const float s = __sinf(th), c = __cosf(th);
        const float kx = 50.0f * c, ky = 50.0f * s;
        const float sig = __expf(lsA[b]) + 0.001f;
        const float is2 = 1.0f / (sig * sig);
        sP0[b] = make_float4(kx, ky, x0A[b], y0A[b]);
        sP1[b] = make_float4(reA[b], imA[b], is2, DD * is2);
        sP2[b] = make_float4(__cosf(kx * DD), __sinf(kx * DD),
                             __cosf(ky * DD), __sinf(ky * DD));
        sW[b]  = __expf(-2.0f * DD * DD * is2);
    }
    __syncthreads();

    // ---- eval decode: side (A rows / B cols), beam pair, row group ----
    const int side = t >> 8;          // wave-uniform: waves 0-3 = A, 4-7 = B
    const int u    = t & 255;
    const int bp   = u & 15;          // beams bp*2, bp*2+1 within tile
    const int rg   = u >> 4;          // rows rg + r*16, r = 0..7
    const float x0r = -1.0f + (float)((side ? n0 : m0) + rg) * STEP;
    f16* const evBase = side ? &smB[0][0][0] : &smA[0][0][0];
    const int e00 = rg * 32 + ((bp * 2) ^ ((rg & 3) << 3));

    #define EVAL(bf, kt)                                                      \
    do {                                                                      \
        float vRe[2], vIm[2], rho[2], cdv[2], sdv[2], wv[2];                  \
        _Pragma("unroll")                                                     \
        for (int jb = 0; jb < 2; ++jb) {                                      \
            const int b_ = (kt) * BK + bp * 2 + jb;                           \
            const float4 p0 = sP0[b_];                                        \
            const float4 p1 = sP1[b_];                                        \
            const float4 p2 = sP2[b_];                                        \
            const float k_ = side ? p0.y : p0.x;                              \
            const float p_ = side ? p0.w : p0.z;                              \
            cdv[jb] = side ? p2.z : p2.x;                                     \
            sdv[jb] = side ? p2.w : p2.y;                                     \
            wv[jb]  = sW[b_];                                                 \
            const float phi = k_ * x0r;                                       \
            const float sn = __sinf(phi), cs = __cosf(phi);                   \
            const float dx = x0r - p_;                                        \
            const float e0 = __expf(-dx * dx * p1.z);                         \
            rho[jb] = __expf(-(2.0f * dx + DD) * p1.w);                       \
            if (side) { vRe[jb] = e0 * cs; vIm[jb] = e0 * sn; }               \
            else {                                                            \
                vRe[jb] = e0 * (p1.x * cs - p1.y * sn);                       \
                vIm[jb] = e0 * (p1.x * sn + p1.y * cs);                       \
            }                                                                 \
        }                                                                     \
        const int eb = (bf) * 2 * PL32 + e00;                                 \
        _Pragma("unroll")                                                     \
        for (int r = 0; r < 8; ++r) {                                         \
            *(unsigned int*)&evBase[eb + r * 512]        = pk2(vRe[0], vRe[1]); \
            *(unsigned int*)&evBase[eb + PL32 + r * 512] = pk2(vIm[0], vIm[1]); \
            _Pragma("unroll")                                                 \
            for (int jb = 0; jb < 2; ++jb) {                                  \
                const float t1 = vRe[jb] * cdv[jb] - vIm[jb] * sdv[jb];       \
                const float t2 = vRe[jb] * sdv[jb] + vIm[jb] * cdv[jb];       \
                vRe[jb] = t1 * rho[jb];                                       \
                vIm[jb] = t2 * rho[jb];                                       \
                rho[jb] *= wv[jb];                                            \
            }                                                                 \
        }                                                                     \
    } while (0)

    // ---- fragment LDS element-offsets (swizzled, within a buffer) ----
    const int xk = (la & 3) << 3;
    int offA[2][2], offBf[2];
    #pragma unroll
    for (int ks = 0; ks < 2; ++ks) {
        #pragma unroll
        for (int sub = 0; sub < 2; ++sub)
            offA[sub][ks] = (wm * 64 + sub * 32 + la) * 32
                          + ((ks * 16 + lg * 8) ^ xk);
        offBf[ks] = (wn * 32 + la) * 32 + ((ks * 16 + lg * 8) ^ xk);
    }

    f32x16 accRe0 = (f32x16)0.0f, accIm0 = (f32x16)0.0f;
    f32x16 accRe1 = (f32x16)0.0f, accIm1 = (f32x16)0.0f;

    // ---- k-tile 0 ----
    EVAL(0, 0);
    __syncthreads();

    for (int kt = 0; kt < NKT; ++kt) {
        const int cur = kt & 1;
        const f16* sA = &smA[0][0][0] + cur * 2 * PL32;
        const f16* sB = &smB[0][0][0] + cur * 2 * PL32;

        __builtin_amdgcn_s_setprio(1);
        #pragma unroll
        for (int ks = 0; ks < 2; ++ks) {
            const f16x8 aR0 = *(const f16x8*)&sA[offA[0][ks]];
            const f16x8 aR1 = *(const f16x8*)&sA[offA[1][ks]];
            const f16x8 aI0 = *(const f16x8*)&sA[PL32 + offA[0][ks]];
            const f16x8 aI1 = *(const f16x8*)&sA[PL32 + offA[1][ks]];
            const f16x8 bR  = *(const f16x8*)&sB[offBf[ks]];
            const f16x8 bI  = *(const f16x8*)&sB[PL32 + offBf[ks]];
            const f16x8 bN  = neg8(bI);

            accRe0 = __builtin_amdgcn_mfma_f32_32x32x16_f16(aR0, bR, accRe0, 0, 0, 0);
            accIm0 = __builtin_amdgcn_mfma_f32_32x32x16_f16(aR0, bI, accIm0, 0, 0, 0);
            accRe1 = __builtin_amdgcn_mfma_f32_32x32x16_f16(aR1, bR, accRe1, 0, 0, 0);
            accIm1 = __builtin_amdgcn_mfma_f32_32x32x16_f16(aR1, bI, accIm1, 0, 0, 0);
            accRe0 = __builtin_amdgcn_mfma_f32_32x32x16_f16(aI0, bN, accRe0, 0, 0, 0);
            accIm0 = __builtin_amdgcn_mfma_f32_32x32x16_f16(aI0, bR, accIm0, 0, 0, 0);
            accRe1 = __builtin_amdgcn_mfma_f32_32x32x16_f16(aI1, bN, accRe1, 0, 0, 0);
            accIm1 = __builtin_amdgcn_mfma_f32_32x32x16_f16(aI1, bR, accIm1, 0, 0, 0);
        }
        __builtin_amdgcn_s_setprio(0);

        if (kt + 1 < NKT)
            EVAL(cur ^ 1, kt + 1);

        __syncthreads();
    }

    // ---- epilogue: out = Re^2 + Im^2 ----
    // C/D layout (32x32): col = lane&31, row = (reg&3) + 8*(reg>>2) + 4*(lane>>5)
    const int gn     = n0 + wn * 32 + la;
    const int gmBase = m0 + wm * 64;
    #pragma unroll
    for (int r = 0; r < 16; ++r) {
        const int row = (r & 3) + 8 * (r >> 2) + 4 * lg;
        const float er = accRe0[r], ei = accIm0[r];
        out[(size_t)(gmBase + row) * RES + gn] = er * er + ei * ei;
    }
    #pragma unroll
    for (int r = 0; r < 16; ++r) {
        const int row = (r & 3) + 8 * (r >> 2) + 4 * lg;
        const float er = accRe1[r], ei = accIm1[r];
        out[(size_t)(gmBase + 32 + row) * RES + gn] = er * er + ei * ei;
    }
    #undef EVAL
}

// ---------------------------------------------------------------------------
extern "C" void kernel_launch(void* const* d_in, const int* in_sizes, int n_in,
                              void* d_out, int out_size, void* d_ws, size_t ws_size,
                              hipStream_t stream) {
    const float* theta = (const float*)d_in[0];
    const float* reA   = (const float*)d_in[1];
    const float* imA   = (const float*)d_in[2];
    const float* x0A   = (const float*)d_in[3];
    const float* y0A   = (const float*)d_in[4];
    const float* lsA   = (const float*)d_in[5];
    const float* X     = (const float*)d_in[6];
    const float* Y     = (const float*)d_in[7];
    float* out = (float*)d_out;

    ewald_fused<<<256, 512, 0, stream>>>(theta, reA, imA, x0A, y0A, lsA,
                                         X, Y, out);
}

// Round 15
// 22.893 us; speedup vs baseline: 5.1789x; 1.0005x over previous
//
#include <hip/hip_runtime.h>
#include <math.h>

#define RES 2048
#define NB  256
#define PLANE (RES * NB)       // 524288 f16 elements per plane (1 MB)
#define STEP (2.0f / 2047.0f)

typedef _Float16 f16;
typedef _Float16 f16x8 __attribute__((ext_vector_type(8)));
typedef float    f32x16 __attribute__((ext_vector_type(16)));

__device__ __forceinline__ f16x8 neg8(f16x8 v) {
    union { f16x8 h; unsigned int u[4]; } x;
    x.h = v;
    #pragma unroll
    for (int i = 0; i < 4; ++i) x.u[i] ^= 0x80008000u;
    return x.h;
}

// ---------------------------------------------------------------------------
// Fragment-ordered table layout (per plane):
//   value(row, b) lives at  e = chunk*512 + kh*256 + (row&31)*8 + (b&7)
//   with chunk = (row>>5)*16 + (b>>4),  kh = (b>>3)&1.
// This is EXACTLY the mfma_32x32x16_f16 operand lane order: a wave's frag
// load for (row_blk, kt) is  plane + chunk*512 + lane*8  -> one coalesced
// global_load_dwordx4 per lane (1 KB per wave), no LDS needed at all.
// ---------------------------------------------------------------------------

// Kernel 1: build 4 planes {aRe, aIm (coeff folded), bRe, bIm} in d_ws.
// 65536 threads; thread -> (grow = w>>4 *32 + (l&31), b0 = (w&15)*16 + (l>>5)*8).
// Writes: 4 x dwordx4 at e = w*512 + (l>>5)*256 + (l&31)*8 -> wave-contiguous.
__global__ __launch_bounds__(256) void tables_frag(
    const float* __restrict__ theta, const float* __restrict__ reA,
    const float* __restrict__ imA, const float* __restrict__ x0A,
    const float* __restrict__ y0A, const float* __restrict__ lsA,
    f16* __restrict__ ws)
{
    f16* aRe = ws;
    f16* aIm = ws + PLANE;
    f16* bRe = ws + 2 * PLANE;
    f16* bIm = ws + 3 * PLANE;

    const int gid = blockIdx.x * 256 + threadIdx.x;
    const int l   = gid & 63;
    const int w   = gid >> 6;              // chunk id 0..1023
    const int grow = (w >> 4) * 32 + (l & 31);
    const int b0   = (w & 15) * 16 + (l >> 5) * 8;
    const int e    = w * 512 + (l >> 5) * 256 + (l & 31) * 8;

    const float xv = -1.0f + (float)grow * STEP;  // same value for x_i and y_j

    float aRv[8], aIv[8], bRv[8], bIv[8];
    #pragma unroll
    for (int j = 0; j < 8; ++j) {
        const int b = b0 + j;
        const float th  = theta[b];
        const float sth = __sinf(th), cth = __cosf(th);
        const float kx = 50.0f * cth, ky = 50.0f * sth;
        const float sig = __expf(lsA[b]) + 0.001f;
        const float is2 = 1.0f / (sig * sig);
        const float re = reA[b], im = imA[b];

        const float phx = kx * xv;
        const float snx = __sinf(phx), csx = __cosf(phx);
        const float dx = xv - x0A[b];
        const float ex = __expf(-dx * dx * is2);
        aRv[j] = ex * (re * csx - im * snx);
        aIv[j] = ex * (re * snx + im * csx);

        const float phy = ky * xv;
        const float sny = __sinf(phy), csy = __cosf(phy);
        const float dy = xv - y0A[b];
        const float ey = __expf(-dy * dy * is2);
        bRv[j] = ey * csy;
        bIv[j] = ey * sny;
    }

    union { f16 h[8]; float4 v; } p;
    #pragma unroll
    for (int j = 0; j < 8; ++j) p.h[j] = (f16)aRv[j];
    *(float4*)&aRe[e] = p.v;
    #pragma unroll
    for (int j = 0; j < 8; ++j) p.h[j] = (f16)aIv[j];
    *(float4*)&aIm[e] = p.v;
    #pragma unroll
    for (int j = 0; j < 8; ++j) p.h[j] = (f16)bRv[j];
    *(float4*)&bRe[e] = p.v;
    #pragma unroll
    for (int j = 0; j < 8; ++j) p.h[j] = (f16)bIv[j];
    *(float4*)&bIm[e] = p.v;
}

// ---------------------------------------------------------------------------
// Kernel 2: complex GEMM, fragments loaded DIRECTLY from the frag-ordered
// tables (L1/L2-resident). No LDS, no barriers; 1-tile register prefetch.
// 512 threads = 8 waves (2M x 4N), wave tile 64x32, BK=16, 16 k-tiles.
// ---------------------------------------------------------------------------
__global__ __launch_bounds__(512) void gemm_frag(
    const f16* __restrict__ ws, float* __restrict__ out)
{
    const f16* aRe = ws;
    const f16* aIm = ws + PLANE;
    const f16* bRe = ws + 2 * PLANE;
    const f16* bIm = ws + 3 * PLANE;

    const int t    = threadIdx.x;
    const int lane = t & 63;
    const int wave = t >> 6;       // 0..7
    const int wm   = wave >> 2;    // 0..1 -> M offset 64
    const int wn   = wave & 3;     // 0..3 -> N offset 32
    const int la   = lane & 31;
    const int lg   = lane >> 5;

    // XCD-aware swizzle (256 blocks, 8 XCDs)
    const int flat = blockIdx.x;
    const int swz  = (flat & 7) * 32 + (flat >> 3);
    const int m0   = (swz >> 4) * 128;
    const int n0   = (swz & 15) * 128;

    // fragment base element offsets at kt=0 (advance by +512 per k-tile)
    const int laneOff = lg * 256 + la * 8;
    const int cA0 = ((m0 >> 5) + wm * 2 + 0) * 16;   // chunk ids
    const int cA1 = ((m0 >> 5) + wm * 2 + 1) * 16;
    const int cB  = ((n0 >> 5) + wn) * 16;

    const f16* pAR0 = aRe + cA0 * 512 + laneOff;
    const f16* pAR1 = aRe + cA1 * 512 + laneOff;
    const f16* pAI0 = aIm + cA0 * 512 + laneOff;
    const f16* pAI1 = aIm + cA1 * 512 + laneOff;
    const f16* pBR  = bRe + cB  * 512 + laneOff;
    const f16* pBI  = bIm + cB  * 512 + laneOff;

    f32x16 accRe0 = (f32x16)0.0f, accIm0 = (f32x16)0.0f;
    f32x16 accRe1 = (f32x16)0.0f, accIm1 = (f32x16)0.0f;

    // prologue: load k-tile 0 fragments
    f16x8 aR0 = *(const f16x8*)pAR0;
    f16x8 aR1 = *(const f16x8*)pAR1;
    f16x8 aI0 = *(const f16x8*)pAI0;
    f16x8 aI1 = *(const f16x8*)pAI1;
    f16x8 bR  = *(const f16x8*)pBR;
    f16x8 bI  = *(const f16x8*)pBI;

    for (int kt = 0; kt < 16; ++kt) {
        // prefetch next tile's fragments (index clamped; last iter unused)
        const int nx = ((kt + 1) & 15) * 512;
        const f16x8 nR0 = *(const f16x8*)(pAR0 + nx);
        const f16x8 nR1 = *(const f16x8*)(pAR1 + nx);
        const f16x8 nI0 = *(const f16x8*)(pAI0 + nx);
        const f16x8 nI1 = *(const f16x8*)(pAI1 + nx);
        const f16x8 nBR = *(const f16x8*)(pBR  + nx);
        const f16x8 nBI = *(const f16x8*)(pBI  + nx);

        const f16x8 bN = neg8(bI);
        __builtin_amdgcn_s_setprio(1);
        accRe0 = __builtin_amdgcn_mfma_f32_32x32x16_f16(aR0, bR, accRe0, 0, 0, 0);
        accIm0 = __builtin_amdgcn_mfma_f32_32x32x16_f16(aR0, bI, accIm0, 0, 0, 0);
        accRe1 = __builtin_amdgcn_mfma_f32_32x32x16_f16(aR1, bR, accRe1, 0, 0, 0);
        accIm1 = __builtin_amdgcn_mfma_f32_32x32x16_f16(aR1, bI, accIm1, 0, 0, 0);
        accRe0 = __builtin_amdgcn_mfma_f32_32x32x16_f16(aI0, bN, accRe0, 0, 0, 0);
        accIm0 = __builtin_amdgcn_mfma_f32_32x32x16_f16(aI0, bR, accIm0, 0, 0, 0);
        accRe1 = __builtin_amdgcn_mfma_f32_32x32x16_f16(aI1, bN, accRe1, 0, 0, 0);
        accIm1 = __builtin_amdgcn_mfma_f32_32x32x16_f16(aI1, bR, accIm1, 0, 0, 0);
        __builtin_amdgcn_s_setprio(0);

        aR0 = nR0; aR1 = nR1; aI0 = nI0; aI1 = nI1; bR = nBR; bI = nBI;
    }

    // epilogue: out = Re^2 + Im^2
    // C/D layout (32x32): col = lane&31, row = (reg&3) + 8*(reg>>2) + 4*(lane>>5)
    const int gn     = n0 + wn * 32 + la;
    const int gmBase = m0 + wm * 64;
    #pragma unroll
    for (int r = 0; r < 16; ++r) {
        const int row = (r & 3) + 8 * (r >> 2) + 4 * lg;
        const float er = accRe0[r], ei = accIm0[r];
        out[(size_t)(gmBase + row) * RES + gn] = er * er + ei * ei;
    }
    #pragma unroll
    for (int r = 0; r < 16; ++r) {
        const int row = (r & 3) + 8 * (r >> 2) + 4 * lg;
        const float er = accRe1[r], ei = accIm1[r];
        out[(size_t)(gmBase + 32 + row) * RES + gn] = er * er + ei * ei;
    }
}

// ---------------------------------------------------------------------------
// Fallback: direct brute force (only if ws_size too small; harness gives 8MB+).
// ---------------------------------------------------------------------------
__global__ __launch_bounds__(256) void ewald_direct(
    const float* __restrict__ theta, const float* __restrict__ reA,
    const float* __restrict__ imA, const float* __restrict__ x0A,
    const float* __restrict__ y0A, const float* __restrict__ lsA,
    const float* __restrict__ X, const float* __restrict__ Y,
    float* __restrict__ out)
{
    __shared__ float kxs[NB], kys[NB], res[NB], ims[NB], pxs[NB], pys[NB], is2s[NB];
    const int t = threadIdx.x;
    if (t < NB) {
        const float th  = theta[t];
        const float sig = __expf(lsA[t]) + 0.001f;
        kxs[t] = 50.0f * __cosf(th);
        kys[t] = 50.0f * __sinf(th);
        res[t] = reA[t]; ims[t] = imA[t];
        pxs[t] = x0A[t]; pys[t] = y0A[t];
        is2s[t] = 1.0f / (sig * sig);
    }
    __syncthreads();
    const size_t npix = (size_t)RES * RES;
    for (size_t idx = (size_t)blockIdx.x * blockDim.x + t; idx < npix;
         idx += (size_t)gridDim.x * blockDim.x) {
        const float xv = X[idx], yv = Y[idx];
        float er = 0.f, ei = 0.f;
        for (int b = 0; b < NB; ++b) {
            const float dx = xv - pxs[b], dy = yv - pys[b];
            const float env = __expf(-(dx * dx + dy * dy) * is2s[b]);
            const float ph = kxs[b] * xv + kys[b] * yv;
            float s, c;
            __sincosf(ph, &s, &c);
            er += env * (res[b] * c - ims[b] * s);
            ei += env * (res[b] * s + ims[b] * c);
        }
        out[idx] = er * er + ei * ei;
    }
}

// ---------------------------------------------------------------------------
extern "C" void kernel_launch(void* const* d_in, const int* in_sizes, int n_in,
                              void* d_out, int out_size, void* d_ws, size_t ws_size,
                              hipStream_t stream) {
    const float* theta = (const float*)d_in[0];
    const float* reA   = (const float*)d_in[1];
    const float* imA   = (const float*)d_in[2];
    const float* x0A   = (const float*)d_in[3];
    const float* y0A   = (const float*)d_in[4];
    const float* lsA   = (const float*)d_in[5];
    const float* X     = (const float*)d_in[6];
    const float* Y     = (const float*)d_in[7];
    float* out = (float*)d_out;

    const size_t need = 4 * (size_t)PLANE * sizeof(f16);   // 4 MB

    if (ws_size >= need) {
        f16* ws = (f16*)d_ws;
        tables_frag<<<256, 256, 0, stream>>>(theta, reA, imA, x0A, y0A, lsA, ws);
        gemm_frag<<<256, 512, 0, stream>>>(ws, out);
    } else {
        ewald_direct<<<2048, 256, 0, stream>>>(theta, reA, imA, x0A, y0A, lsA,
                                               X, Y, out);
    }
}